// Round 10
// baseline (1027.748 us; speedup 1.0000x reference)
//
#include <hip/hip_runtime.h>

#define NEGF (-1e30f)

typedef __attribute__((ext_vector_type(8))) short short8;
typedef __attribute__((ext_vector_type(4))) float float4v;

template <bool V> struct BC { static constexpr bool value = V; };

__device__ __forceinline__ short f2bf(float f) {
  union { float f; unsigned u; } v; v.f = f;
  unsigned r = v.u + 0x7fffu + ((v.u >> 16) & 1u);  // RNE truncate to bf16
  return (short)(r >> 16);
}
__device__ __forceinline__ float fastrcp(float x) { return __builtin_amdgcn_rcpf(x); }
__device__ __forceinline__ float sigf(float x) { return fastrcp(1.0f + __expf(-x)); }
__device__ __forceinline__ float tanhfast(float x) { return 1.0f - 2.0f * fastrcp(__expf(2.0f * x) + 1.0f); }

// ---------------------------------------------------------------------------
// prep: stage Wcat = [Wh1;Wh2] (256x640 f32) into bf16 MFMA B-fragment layout.
// frag f = (q*8+g)*8+kk; lane holds B[k][n], k=kk*32+(lane>>4)*8+j,
// n = (q*8+g)*16 + (lane&15); 16B per lane.
__global__ void prep_w_kernel(const float* __restrict__ Wh1, const float* __restrict__ Wh2,
                              short* __restrict__ wsW) {
  int t = blockIdx.x * 256 + threadIdx.x;   // 0..20479
  int lane = t & 63;
  int frag = t >> 6;                        // 0..319
  int nt = frag >> 3, kk = frag & 7;
  int n  = nt * 16 + (lane & 15);
  int kb = kk * 32 + (lane >> 4) * 8;
  short8 v;
#pragma unroll
  for (int j = 0; j < 8; ++j) {
    int k = kb + j;
    float w = (k < 128) ? Wh1[k * 640 + n] : Wh2[(k - 128) * 640 + n];
    v[j] = f2bf(w);
  }
  ((short8*)wsW)[frag * 64 + lane] = v;
}

// ---------------------------------------------------------------------------
// MDLSTM wavefront: 1 batch/block (32 blocks), 8 waves, 1 barrier/diagonal.
// bf16 matmul (fp8 failed accuracy in R9: absmax 304 vs 73.6).
// LDS budget (162.8 KB of 160 KiB):
//  - wlds: 125 weight frags (gates 3,4 minus 3) resident       128.0 KB
//  - h double-buffer (bf16)                                     17.4 KB
//  - feat RING window: 33 cols x 132 stride (feat accumulation  17.4 KB
//    stays in LDS; each column hits HBM once when complete)
// Streamed from L2/diag: gates 0,1,2 + 3 frags = 195 KB (VMEM pipe).
// Removes the 32 KB/diag feat RMW and its L2-latency chain entirely.
__global__ __launch_bounds__(512)
void mdlstm_kernel(const float* __restrict__ X, const short* __restrict__ wsW,
                   const float* __restrict__ Wx, const float* __restrict__ bias,
                   float* __restrict__ feat) {
  __shared__ __align__(16) short h_buf[2][32][136];   // 17,408 B
  __shared__ __align__(16) short wlds[125 * 512];     // 128,000 B: frags 192..316
  __shared__ float ring[33 * 132];                    // 17,424 B feat window

  const int b    = blockIdx.x;
  const int tid  = threadIdx.x;
  const int lane = tid & 63;
  const int g    = tid >> 6;       // wave 0..7
  const int col  = lane & 15;
  const int quad = lane >> 4;
  const int jj   = g * 16 + col;   // h-feature column this lane owns

  for (int i = tid; i < 2 * 32 * 136 / 2; i += 512) ((int*)h_buf)[i] = 0;
  {
    const uint4* src = (const uint4*)(wsW + 192 * 512);  // frags 192..316 contiguous
    uint4* dst = (uint4*)wlds;
    for (int i = tid; i < 8000; i += 512) dst[i] = src[i];
  }
  for (int i = tid; i < 33 * 132; i += 512) ring[i] = 0.0f;

  float wx[5], bg[5];
#pragma unroll
  for (int q = 0; q < 5; ++q) {
    wx[q] = Wx[q * 128 + jj];
    bg[q] = bias[q * 128 + jj];
  }
  float cp[2][4];   // c-state in registers: [mt][r], row = mt*16+quad*4+r
#pragma unroll
  for (int mt = 0; mt < 2; ++mt)
#pragma unroll
    for (int r = 0; r < 4; ++r) cp[mt][r] = 0.0f;

  const float* Xg = X + b * 8192;
  float* fb = feat + b * 32768;
  const short8* W8 = (const short8*)wsW;
  const int col48 = col + 48;
  __syncthreads();

  // flush completed feat column w = d-32 (done at diag d-1, idle at diag d)
  auto flush = [&](int d) {
    int wf = d - 32;
    if (wf >= 0 && tid < 128) {
      int sf = wf % 33;
      fb[wf * 128 + tid] = ring[sf * 132 + tid];
      ring[sf * 132 + tid] = 0.0f;    // fresh for column wf+33 (first write diag wf+33)
    }
  };

  auto step = [&](int d, auto c0, auto c1, auto cv) {
    constexpr bool DO0 = decltype(c0)::value;   // rows 0..15 active
    constexpr bool DO1 = decltype(c1)::value;   // rows 16..31 active
    constexpr bool ALLV = decltype(cv)::value;  // all w in-range (no checks)
    const int rbuf = (d + 1) & 1, wbuf = d & 1;
    const int sd = d % 33;

    float4v acc[5][2];
#pragma unroll
    for (int q = 0; q < 5; ++q) {
      if (DO0) acc[q][0] = (float4v){bg[q], bg[q], bg[q], bg[q]};
      if (DO1) acc[q][1] = (float4v){bg[q], bg[q], bg[q], bg[q]};
    }
    const short8 z8 = (short8){0, 0, 0, 0, 0, 0, 0, 0};
#pragma unroll
    for (int kk = 0; kk < 8; ++kk) {
      const int up = (kk >= 4) ? 1 : 0;           // kk<4: h_left; kk>=4: h_up
      const int cc = (kk & 3) * 32 + quad * 8;
      short8 a0, a1;
      if (DO0) {
        int row = col - up;
        a0 = (row >= 0) ? *(const short8*)&h_buf[rbuf][row][cc] : z8;
      }
      if (DO1) {
        int row = 16 + col - up;
        a1 = *(const short8*)&h_buf[rbuf][row][cc];
      }
#pragma unroll
      for (int q = 0; q < 5; ++q) {
        short8 bw;
        if (q < 3)       bw = W8[((q * 8 + g) * 8 + kk) * 64 + lane];              // L2 stream
        else if (q == 3) bw = *(const short8*)&wlds[((g * 8 + kk)) * 512 + lane * 8];
        else if (g == 7 && kk >= 5) bw = W8[((4 * 8 + 7) * 8 + kk) * 64 + lane];   // 3 overflow frags
        else             bw = *(const short8*)&wlds[((64 + g * 8 + kk)) * 512 + lane * 8];
        if (DO0) acc[q][0] = __builtin_amdgcn_mfma_f32_16x16x32_bf16(a0, bw, acc[q][0], 0, 0, 0);
        if (DO1) acc[q][1] = __builtin_amdgcn_mfma_f32_16x16x32_bf16(a1, bw, acc[q][1], 0, 0, 0);
      }
    }

    // ---- epilogue: c_up exchange (old values), hoisted x loads ----
    float t0 = __shfl_up(cp[0][3], 16);
    float t1 = __shfl_up(cp[1][3], 16);
    float tx = __shfl(cp[0][3], col48);            // quad3's row-15 c
    float cuA[4] = {quad ? t0 : 0.0f, cp[0][0], cp[0][1], cp[0][2]};
    float cuB[4] = {quad ? t1 : tx,   cp[1][0], cp[1][1], cp[1][2]};

    float xm[2][4];
#pragma unroll
    for (int mt = 0; mt < 2; ++mt) {
      if ((mt == 0 && !DO0) || (mt == 1 && !DO1)) continue;
      const int m0 = mt * 16 + quad * 4;
#pragma unroll
      for (int r = 0; r < 4; ++r) {
        int w = d - (m0 + r);
        if (ALLV || (w >= 0 && w < 256)) xm[mt][r] = Xg[w * 32 + (m0 + r)];
      }
    }
#pragma unroll
    for (int mt = 0; mt < 2; ++mt) {
      if ((mt == 0 && !DO0) || (mt == 1 && !DO1)) continue;
      const int m0 = mt * 16 + quad * 4;
#pragma unroll
      for (int r = 0; r < 4; ++r) {
        const int m = m0 + r;          // C/D layout: row = quad*4 + reg
        const int w = d - m;
        if (ALLV || (w >= 0 && w < 256)) {
          float c_up = mt ? cuB[r] : cuA[r];
          float c_l  = cp[mt][r];
          float x    = xm[mt][r];
          float zi = fmaf(x, wx[0], acc[0][mt][r]);
          float zg = fmaf(x, wx[1], acc[1][mt][r]);
          float z1 = fmaf(x, wx[2], acc[2][mt][r]);
          float z2 = fmaf(x, wx[3], acc[3][mt][r]);
          float zo = fmaf(x, wx[4], acc[4][mt][r]);
          float c = sigf(z1) * c_l + sigf(z2) * c_up + sigf(zi) * tanhfast(zg);
          float h = sigf(zo) * tanhfast(c);
          cp[mt][r] = c;
          h_buf[wbuf][m][jj] = f2bf(h);
          int s = sd - m; s += (s >> 31) & 33;     // (d-m) mod 33
          ring[s * 132 + jj] += h;                 // LDS feat accumulation
        }
      }
    }
  };

  BC<true> T; BC<false> F;
  for (int d = 0;   d < 16;  ++d) { flush(d); step(d, T, F, F); __syncthreads(); }
  for (int d = 16;  d < 31;  ++d) { flush(d); step(d, T, T, F); __syncthreads(); }
  for (int d = 31;  d < 256; ++d) { flush(d); step(d, T, T, T); __syncthreads(); }
  for (int d = 256; d < 271; ++d) { flush(d); step(d, T, T, F); __syncthreads(); }
  for (int d = 271; d < 287; ++d) { flush(d); step(d, F, T, F); __syncthreads(); }
  // last column (w=255, completed at diag 286)
  if (tid < 128) fb[255 * 128 + tid] = ring[(255 % 33) * 132 + tid];
}

// ---------------------------------------------------------------------------
// logits = feat @ W_fc + b_fc, then log_softmax -> logp [32][256][101]
__global__ __launch_bounds__(256)
void logits_kernel(const float* __restrict__ feat, const float* __restrict__ Wfc,
                   const float* __restrict__ bfc, float* __restrict__ logp) {
  __shared__ float sW[128 * 101];
  __shared__ float sF[8][128];
  __shared__ float sL[8][104];
  __shared__ float sLse[8];
  const int tid = threadIdx.x;
  const int b  = blockIdx.x >> 5;
  const int t0 = (blockIdx.x & 31) * 8;

  for (int i = tid; i < 128 * 101; i += 256) sW[i] = Wfc[i];
  for (int i = tid; i < 8 * 128; i += 256)
    sF[i >> 7][i & 127] = feat[(b * 256 + t0 + (i >> 7)) * 128 + (i & 127)];
  __syncthreads();
  for (int idx = tid; idx < 8 * 101; idx += 256) {
    int tr = idx / 101, v = idx - tr * 101;
    float s = bfc[v];
#pragma unroll 4
    for (int k = 0; k < 128; ++k) s += sF[tr][k] * sW[k * 101 + v];
    sL[tr][v] = s;
  }
  __syncthreads();
  if (tid < 8) {
    float m = NEGF;
    for (int v = 0; v < 101; ++v) m = fmaxf(m, sL[tid][v]);
    float su = 0.0f;
    for (int v = 0; v < 101; ++v) su += __expf(sL[tid][v] - m);
    sLse[tid] = m + __logf(su);
  }
  __syncthreads();
  for (int idx = tid; idx < 8 * 101; idx += 256) {
    int tr = idx / 101, v = idx - tr * 101;
    logp[(b * 256 + t0 + tr) * 101 + v] = sL[tr][v] - sLse[tr];
  }
}

// ---------------------------------------------------------------------------
// CTC forward: one wave per batch. Lane l holds alpha[s=l]; lane 63 also s=64.
// 4-deep rotating prefetch hides L2 latency on the logp reads.
__global__ __launch_bounds__(64)
void ctc_kernel(const float* __restrict__ logp, const int* __restrict__ y,
                float* __restrict__ out) {
  const int b = blockIdx.x;
  const int l = threadIdx.x;
  const float* lpb = logp + b * 256 * 101;
  const int* yb = y + b * 32;
  int lab = (l & 1) ? yb[l >> 1] : 100;                 // ext[s]: odd->label, even->blank
  bool skip = (l & 1) && (l >= 3) && (yb[l >> 1] != yb[(l >> 1) - 1]);

  float a   = (l == 0) ? lpb[100] : ((l == 1) ? lpb[lab] : NEGF);
  float a64 = NEGF;                                      // alpha[64] (valid on lane 63)
  float pl[4], pb[4];
#pragma unroll
  for (int tt = 0; tt < 4; ++tt) {
    pl[tt] = lpb[(1 + tt) * 101 + lab];
    pb[tt] = lpb[(1 + tt) * 101 + 100];
  }
#pragma unroll 4
  for (int t = 1; t < 256; ++t) {
    const int s = (t - 1) & 3;
    float lpl = pl[s], lpbk = pb[s];
    if (t + 4 < 256) {                                   // refill slot with t+4
      pl[s] = lpb[(t + 4) * 101 + lab];
      pb[s] = lpb[(t + 4) * 101 + 100];
    }
    float am1 = __shfl_up(a, 1); if (l == 0) am1 = NEGF;
    float am2 = __shfl_up(a, 2); if (l < 2 || !skip) am2 = NEGF;
    float m3 = fmaxf(a, fmaxf(am1, am2));
    float na = m3 + __logf(__expf(a - m3) + __expf(am1 - m3) + __expf(am2 - m3)) + lpl;
    float m2 = fmaxf(a64, a);                            // s=64: lse(alpha64, alpha63)
    float na64 = m2 + __logf(__expf(a64 - m2) + __expf(a - m2)) + lpbk;
    a = na;
    a64 = na64;
  }
  float A63 = __shfl(a, 63);
  float A64 = __shfl(a64, 63);
  if (l == 0) {
    float m = fmaxf(A63, A64);
    out[b] = -(m + __logf(__expf(A63 - m) + __expf(A64 - m)));
  }
}

// ---------------------------------------------------------------------------
extern "C" void kernel_launch(void* const* d_in, const int* in_sizes, int n_in,
                              void* d_out, int out_size, void* d_ws, size_t ws_size,
                              hipStream_t stream) {
  const float* X   = (const float*)d_in[0];
  const int*   y   = (const int*)d_in[1];
  const float* Wx  = (const float*)d_in[2];
  const float* Wh1 = (const float*)d_in[3];
  const float* Wh2 = (const float*)d_in[4];
  const float* bi  = (const float*)d_in[5];
  const float* Wfc = (const float*)d_in[6];
  const float* bfc = (const float*)d_in[7];
  float* out = (float*)d_out;

  char* ws = (char*)d_ws;
  short* wsW  = (short*)(ws);              // 327,680 B staged bf16 weight frags
  float* feat = (float*)(ws + 0x50000);    // 4 MiB feat (written once per column)
  float* logp = (float*)(ws + 0x450000);   // 3.31 MB log-probs

  prep_w_kernel<<<80, 256, 0, stream>>>(Wh1, Wh2, wsW);
  mdlstm_kernel<<<32, 512, 0, stream>>>(X, wsW, Wx, bi, feat);
  logits_kernel<<<1024, 256, 0, stream>>>(feat, Wfc, bfc, logp);
  ctc_kernel<<<32, 64, 0, stream>>>(logp, y, out);
}

// Round 11
// 960.861 us; speedup vs baseline: 1.0696x; 1.0696x over previous
//
#include <hip/hip_runtime.h>

#define NEGF (-1e30f)

typedef __attribute__((ext_vector_type(8))) short short8;
typedef __attribute__((ext_vector_type(4))) float float4v;

template <bool V> struct BC { static constexpr bool value = V; };

__device__ __forceinline__ short f2bf(float f) {
  union { float f; unsigned u; } v; v.f = f;
  unsigned r = v.u + 0x7fffu + ((v.u >> 16) & 1u);  // RNE truncate to bf16
  return (short)(r >> 16);
}
__device__ __forceinline__ float fastrcp(float x) { return __builtin_amdgcn_rcpf(x); }
__device__ __forceinline__ float clamp15(float x) { return fminf(15.0f, fmaxf(-15.0f, x)); }

// ---------------------------------------------------------------------------
// prep: stage Wcat = [Wh1;Wh2] (256x640 f32) into bf16 MFMA B-fragment layout.
// frag f = (q*8+g)*8+kk; lane holds B[k][n], k=kk*32+(lane>>4)*8+j,
// n = (q*8+g)*16 + (lane&15); 16B per lane.
__global__ void prep_w_kernel(const float* __restrict__ Wh1, const float* __restrict__ Wh2,
                              short* __restrict__ wsW) {
  int t = blockIdx.x * 256 + threadIdx.x;   // 0..20479
  int lane = t & 63;
  int frag = t >> 6;                        // 0..319
  int nt = frag >> 3, kk = frag & 7;
  int n  = nt * 16 + (lane & 15);
  int kb = kk * 32 + (lane >> 4) * 8;
  short8 v;
#pragma unroll
  for (int j = 0; j < 8; ++j) {
    int k = kb + j;
    float w = (k < 128) ? Wh1[k * 640 + n] : Wh2[(k - 128) * 640 + n];
    v[j] = f2bf(w);
  }
  ((short8*)wsW)[frag * 64 + lane] = v;
}

// ---------------------------------------------------------------------------
// MDLSTM wavefront: 1 batch/block (32 blocks), 8 waves, 1 barrier/diagonal.
// R8 structure (proven 858 us) + VALU diet (R10 showed VMEM is NOT binding):
//  - 8-transcendental LSTM cell (common denominator; HW-validated in R3)
//  - diagonal-invariant weight addresses hoisted to VGPR base pointers with
//    compile-time immediate offsets (kk*1024 fits 13-bit glb / 16-bit ds imm)
//  - per-diag x/feat pointers with -31*m / -128*r immediates
__global__ __launch_bounds__(512)
void mdlstm_kernel(const float* __restrict__ X, const short* __restrict__ wsW,
                   const float* __restrict__ Wx, const float* __restrict__ bias,
                   float* __restrict__ feat) {
  __shared__ __align__(16) short h_buf[2][32][136];   // 17.4 KB: h double-buffer
  __shared__ __align__(16) short wlds[128 * 512];     // 128 KB: gates 3,4 frags
  __shared__ __align__(16) short wlds2[8 * 512];      // 8 KB: gate 2, kk=0 frags

  const int b    = blockIdx.x;
  const int tid  = threadIdx.x;
  const int lane = tid & 63;
  const int g    = tid >> 6;       // wave 0..7
  const int col  = lane & 15;
  const int quad = lane >> 4;
  const int jj   = g * 16 + col;   // h-feature column this lane owns

  for (int i = tid; i < 2 * 32 * 136 / 2; i += 512) ((int*)h_buf)[i] = 0;
  {
    const uint4* src = (const uint4*)(wsW + 192 * 512);  // frags 192.. (q=3,4)
    uint4* dst = (uint4*)wlds;
    for (int i = tid; i < 8192; i += 512) dst[i] = src[i];
    const uint4* s2 = (const uint4*)wsW;                 // gate 2, kk=0 frags
    uint4* d2 = (uint4*)wlds2;
    for (int i = tid; i < 512; i += 512) {
      int gg = i >> 6, ln = i & 63;
      d2[i] = s2[(128 + 8 * gg) * 64 + ln];
    }
  }
  {
    float4 z4 = {0.f, 0.f, 0.f, 0.f};
    float4* f4 = (float4*)(feat + b * 32768);
    for (int i = tid; i < 8192; i += 512) f4[i] = z4;
  }

  float wx[5], bg[5];
#pragma unroll
  for (int q = 0; q < 5; ++q) {
    wx[q] = Wx[q * 128 + jj];
    bg[q] = bias[q * 128 + jj];
  }
  float cp[2][4];   // c-state in registers: [mt][r], row = mt*16+quad*4+r
#pragma unroll
  for (int mt = 0; mt < 2; ++mt)
#pragma unroll
    for (int r = 0; r < 4; ++r) cp[mt][r] = 0.0f;

  const float* Xg = X + b * 8192;
  float* fb = feat + b * 32768;
  const short8* W8 = (const short8*)wsW;
  const int col48 = col + 48;

  // diagonal-invariant base pointers (addresses fold to base + small imm)
  const short8* pW0 = W8 + ((0 * 8 + g) * 8) * 64 + lane;
  const short8* pW1 = W8 + ((1 * 8 + g) * 8) * 64 + lane;
  const short8* pW2 = W8 + ((2 * 8 + g) * 8) * 64 + lane;
  const short8* pL3 = (const short8*)&wlds[((0 * 8 + g) * 8) * 512 + lane * 8];
  const short8* pL4 = (const short8*)&wlds[((1 * 8 + g) * 8) * 512 + lane * 8];
  const short8* pL2 = (const short8*)&wlds2[g * 512 + lane * 8];
  const float*  pX  = Xg - 31 * (quad * 4);          // + d*32 per diag
  float*        pF0 = fb + jj - 128 * (quad * 4);    // mt=0, + d*128 per diag
  float*        pF1 = fb + jj - 128 * (16 + quad * 4);
  __syncthreads();

  auto step = [&](int d, auto c0, auto c1, auto cv) {
    constexpr bool DO0 = decltype(c0)::value;   // rows 0..15 active
    constexpr bool DO1 = decltype(c1)::value;   // rows 16..31 active
    constexpr bool ALLV = decltype(cv)::value;  // all w in-range (no checks)
    const int rbuf = (d + 1) & 1, wbuf = d & 1;

    float4v acc[5][2];
#pragma unroll
    for (int q = 0; q < 5; ++q) {
      if (DO0) acc[q][0] = (float4v){bg[q], bg[q], bg[q], bg[q]};
      if (DO1) acc[q][1] = (float4v){bg[q], bg[q], bg[q], bg[q]};
    }
    const short8 z8 = (short8){0, 0, 0, 0, 0, 0, 0, 0};
#pragma unroll
    for (int kk = 0; kk < 8; ++kk) {
      const int up = (kk >= 4) ? 1 : 0;           // kk<4: h_left; kk>=4: h_up
      const int cc = (kk & 3) * 32 + quad * 8;
      short8 a0, a1;
      if (DO0) {
        int row = col - up;
        a0 = (row >= 0) ? *(const short8*)&h_buf[rbuf][row][cc] : z8;
      }
      if (DO1) {
        int row = 16 + col - up;
        a1 = *(const short8*)&h_buf[rbuf][row][cc];
      }
      // ---- LDS-resident gates first (run while VMEM lands) ----
      {
        short8 b3 = pL3[kk * 64];
        if (DO0) acc[3][0] = __builtin_amdgcn_mfma_f32_16x16x32_bf16(a0, b3, acc[3][0], 0, 0, 0);
        if (DO1) acc[3][1] = __builtin_amdgcn_mfma_f32_16x16x32_bf16(a1, b3, acc[3][1], 0, 0, 0);
        short8 b4 = pL4[kk * 64];
        if (DO0) acc[4][0] = __builtin_amdgcn_mfma_f32_16x16x32_bf16(a0, b4, acc[4][0], 0, 0, 0);
        if (DO1) acc[4][1] = __builtin_amdgcn_mfma_f32_16x16x32_bf16(a1, b4, acc[4][1], 0, 0, 0);
      }
      {
        short8 b2 = (kk == 0) ? pL2[0] : pW2[kk * 64];
        if (DO0) acc[2][0] = __builtin_amdgcn_mfma_f32_16x16x32_bf16(a0, b2, acc[2][0], 0, 0, 0);
        if (DO1) acc[2][1] = __builtin_amdgcn_mfma_f32_16x16x32_bf16(a1, b2, acc[2][1], 0, 0, 0);
      }
      {
        short8 b0 = pW0[kk * 64];
        if (DO0) acc[0][0] = __builtin_amdgcn_mfma_f32_16x16x32_bf16(a0, b0, acc[0][0], 0, 0, 0);
        if (DO1) acc[0][1] = __builtin_amdgcn_mfma_f32_16x16x32_bf16(a1, b0, acc[0][1], 0, 0, 0);
        short8 b1 = pW1[kk * 64];
        if (DO0) acc[1][0] = __builtin_amdgcn_mfma_f32_16x16x32_bf16(a0, b1, acc[1][0], 0, 0, 0);
        if (DO1) acc[1][1] = __builtin_amdgcn_mfma_f32_16x16x32_bf16(a1, b1, acc[1][1], 0, 0, 0);
      }
    }

    // ---- epilogue: c_up exchange (old values), hoisted feat+x loads ----
    float t0 = __shfl_up(cp[0][3], 16);
    float t1 = __shfl_up(cp[1][3], 16);
    float tx = __shfl(cp[0][3], col48);            // quad3's row-15 c
    float cuA[4] = {quad ? t0 : 0.0f, cp[0][0], cp[0][1], cp[0][2]};
    float cuB[4] = {quad ? t1 : tx,   cp[1][0], cp[1][1], cp[1][2]};

    const float* pXd = pX + d * 32;
    float* pFd[2] = {pF0 + d * 128, pF1 + d * 128};
    float fo[2][4], xm[2][4];
#pragma unroll
    for (int mt = 0; mt < 2; ++mt) {
      if ((mt == 0 && !DO0) || (mt == 1 && !DO1)) continue;
      const int m0 = mt * 16 + quad * 4;
#pragma unroll
      for (int r = 0; r < 4; ++r) {
        int w = d - (m0 + r);
        if (ALLV || (w >= 0 && w < 256)) {
          fo[mt][r] = pFd[mt][-128 * r];           // early L2 loads
          xm[mt][r] = pXd[-31 * (mt * 16 + r)];
        }
      }
    }
#pragma unroll
    for (int mt = 0; mt < 2; ++mt) {
      if ((mt == 0 && !DO0) || (mt == 1 && !DO1)) continue;
      const int m0 = mt * 16 + quad * 4;
#pragma unroll
      for (int r = 0; r < 4; ++r) {
        const int m = m0 + r;          // C/D layout: row = quad*4 + reg
        const int w = d - m;
        if (ALLV || (w >= 0 && w < 256)) {
          float c_up = mt ? cuB[r] : cuA[r];
          float c_l  = cp[mt][r];
          float x    = xm[mt][r];
          float zi = clamp15(fmaf(x, wx[0], acc[0][mt][r]));
          float zg = clamp15(fmaf(x, wx[1], acc[1][mt][r]));
          float z1 = clamp15(fmaf(x, wx[2], acc[2][mt][r]));
          float z2 = clamp15(fmaf(x, wx[3], acc[3][mt][r]));
          float zo = clamp15(fmaf(x, wx[4], acc[4][mt][r]));
          // common-denominator cell: 6 exp + 2 rcp (HW-validated in R3)
          float e1 = __expf(z1), e2 = __expf(z2), ei = __expf(zi), eg = __expf(2.0f * zg);
          float A1 = 1.0f + e1, A2 = 1.0f + e2, Ai = 1.0f + ei, G = 1.0f + eg;
          float P = Ai * G, Q = A1 * A2;
          float rD = fastrcp(P * Q);
          float c = (e1 * c_l * (A2 * P) + e2 * c_up * (A1 * P) + ei * (eg - 1.0f) * Q) * rD;
          float eo = __expf(-zo);
          float ec = __expf(2.0f * clamp15(c));
          float h = (ec - 1.0f) * fastrcp((1.0f + eo) * (ec + 1.0f));
          cp[mt][r] = c;
          h_buf[wbuf][m][jj] = f2bf(h);
          pFd[mt][-128 * r] = fo[mt][r] + h;       // unique (w,jj) per lane per diag
        }
      }
    }
  };

  BC<true> T; BC<false> F;
  for (int d = 0;   d < 16;  ++d) { step(d, T, F, F); __syncthreads(); }
  for (int d = 16;  d < 31;  ++d) { step(d, T, T, F); __syncthreads(); }
  for (int d = 31;  d < 256; ++d) { step(d, T, T, T); __syncthreads(); }  // no bounds checks
  for (int d = 256; d < 271; ++d) { step(d, T, T, F); __syncthreads(); }
  for (int d = 271; d < 287; ++d) { step(d, F, T, F); __syncthreads(); }
}

// ---------------------------------------------------------------------------
// logits = feat @ W_fc + b_fc, then log_softmax -> logp [32][256][101]
__global__ __launch_bounds__(256)
void logits_kernel(const float* __restrict__ feat, const float* __restrict__ Wfc,
                   const float* __restrict__ bfc, float* __restrict__ logp) {
  __shared__ float sW[128 * 101];
  __shared__ float sF[8][128];
  __shared__ float sL[8][104];
  __shared__ float sLse[8];
  const int tid = threadIdx.x;
  const int b  = blockIdx.x >> 5;
  const int t0 = (blockIdx.x & 31) * 8;

  for (int i = tid; i < 128 * 101; i += 256) sW[i] = Wfc[i];
  for (int i = tid; i < 8 * 128; i += 256)
    sF[i >> 7][i & 127] = feat[(b * 256 + t0 + (i >> 7)) * 128 + (i & 127)];
  __syncthreads();
  for (int idx = tid; idx < 8 * 101; idx += 256) {
    int tr = idx / 101, v = idx - tr * 101;
    float s = bfc[v];
#pragma unroll 4
    for (int k = 0; k < 128; ++k) s += sF[tr][k] * sW[k * 101 + v];
    sL[tr][v] = s;
  }
  __syncthreads();
  if (tid < 8) {
    float m = NEGF;
    for (int v = 0; v < 101; ++v) m = fmaxf(m, sL[tid][v]);
    float su = 0.0f;
    for (int v = 0; v < 101; ++v) su += __expf(sL[tid][v] - m);
    sLse[tid] = m + __logf(su);
  }
  __syncthreads();
  for (int idx = tid; idx < 8 * 101; idx += 256) {
    int tr = idx / 101, v = idx - tr * 101;
    logp[(b * 256 + t0 + tr) * 101 + v] = sL[tr][v] - sLse[tr];
  }
}

// ---------------------------------------------------------------------------
// CTC forward: one wave per batch. Lane l holds alpha[s=l]; lane 63 also s=64.
// 4-deep rotating prefetch hides L2 latency on the logp reads.
__global__ __launch_bounds__(64)
void ctc_kernel(const float* __restrict__ logp, const int* __restrict__ y,
                float* __restrict__ out) {
  const int b = blockIdx.x;
  const int l = threadIdx.x;
  const float* lpb = logp + b * 256 * 101;
  const int* yb = y + b * 32;
  int lab = (l & 1) ? yb[l >> 1] : 100;                 // ext[s]: odd->label, even->blank
  bool skip = (l & 1) && (l >= 3) && (yb[l >> 1] != yb[(l >> 1) - 1]);

  float a   = (l == 0) ? lpb[100] : ((l == 1) ? lpb[lab] : NEGF);
  float a64 = NEGF;                                      // alpha[64] (valid on lane 63)
  float pl[4], pb[4];
#pragma unroll
  for (int tt = 0; tt < 4; ++tt) {
    pl[tt] = lpb[(1 + tt) * 101 + lab];
    pb[tt] = lpb[(1 + tt) * 101 + 100];
  }
#pragma unroll 4
  for (int t = 1; t < 256; ++t) {
    const int s = (t - 1) & 3;
    float lpl = pl[s], lpbk = pb[s];
    if (t + 4 < 256) {                                   // refill slot with t+4
      pl[s] = lpb[(t + 4) * 101 + lab];
      pb[s] = lpb[(t + 4) * 101 + 100];
    }
    float am1 = __shfl_up(a, 1); if (l == 0) am1 = NEGF;
    float am2 = __shfl_up(a, 2); if (l < 2 || !skip) am2 = NEGF;
    float m3 = fmaxf(a, fmaxf(am1, am2));
    float na = m3 + __logf(__expf(a - m3) + __expf(am1 - m3) + __expf(am2 - m3)) + lpl;
    float m2 = fmaxf(a64, a);                            // s=64: lse(alpha64, alpha63)
    float na64 = m2 + __logf(__expf(a64 - m2) + __expf(a - m2)) + lpbk;
    a = na;
    a64 = na64;
  }
  float A63 = __shfl(a, 63);
  float A64 = __shfl(a64, 63);
  if (l == 0) {
    float m = fmaxf(A63, A64);
    out[b] = -(m + __logf(__expf(A63 - m) + __expf(A64 - m)));
  }
}

// ---------------------------------------------------------------------------
extern "C" void kernel_launch(void* const* d_in, const int* in_sizes, int n_in,
                              void* d_out, int out_size, void* d_ws, size_t ws_size,
                              hipStream_t stream) {
  const float* X   = (const float*)d_in[0];
  const int*   y   = (const int*)d_in[1];
  const float* Wx  = (const float*)d_in[2];
  const float* Wh1 = (const float*)d_in[3];
  const float* Wh2 = (const float*)d_in[4];
  const float* bi  = (const float*)d_in[5];
  const float* Wfc = (const float*)d_in[6];
  const float* bfc = (const float*)d_in[7];
  float* out = (float*)d_out;

  char* ws = (char*)d_ws;
  short* wsW  = (short*)(ws);              // 327,680 B staged bf16 weight frags
  float* feat = (float*)(ws + 0x50000);    // 4 MiB feat accumulator (zeroed in-kernel)
  float* logp = (float*)(ws + 0x450000);   // 3.31 MB log-probs

  prep_w_kernel<<<80, 256, 0, stream>>>(Wh1, Wh2, wsW);
  mdlstm_kernel<<<32, 512, 0, stream>>>(X, wsW, Wx, bi, feat);
  logits_kernel<<<1024, 256, 0, stream>>>(feat, Wfc, bfc, logp);
  ctc_kernel<<<32, 64, 0, stream>>>(logp, y, out);
}

// Round 12
// 892.440 us; speedup vs baseline: 1.1516x; 1.0767x over previous
//
#include <hip/hip_runtime.h>

#define NEGF (-1e30f)

typedef __attribute__((ext_vector_type(8))) short short8;
typedef __attribute__((ext_vector_type(4))) float float4v;

template <bool V> struct BC { static constexpr bool value = V; };

__device__ __forceinline__ short f2bf(float f) {
  union { float f; unsigned u; } v; v.f = f;
  unsigned r = v.u + 0x7fffu + ((v.u >> 16) & 1u);  // RNE truncate to bf16
  return (short)(r >> 16);
}
__device__ __forceinline__ float fastrcp(float x) { return __builtin_amdgcn_rcpf(x); }
__device__ __forceinline__ float clamp15(float x) { return fminf(15.0f, fmaxf(-15.0f, x)); }

// ---------------------------------------------------------------------------
// prep: stage Wcat = [Wh1;Wh2] (256x640 f32) into bf16 MFMA B-fragment layout.
__global__ void prep_w_kernel(const float* __restrict__ Wh1, const float* __restrict__ Wh2,
                              short* __restrict__ wsW) {
  int t = blockIdx.x * 256 + threadIdx.x;   // 0..20479
  int lane = t & 63;
  int frag = t >> 6;                        // 0..319
  int nt = frag >> 3, kk = frag & 7;
  int n  = nt * 16 + (lane & 15);
  int kb = kk * 32 + (lane >> 4) * 8;
  short8 v;
#pragma unroll
  for (int j = 0; j < 8; ++j) {
    int k = kb + j;
    float w = (k < 128) ? Wh1[k * 640 + n] : Wh2[(k - 128) * 640 + n];
    v[j] = f2bf(w);
  }
  ((short8*)wsW)[frag * 64 + lane] = v;
}

// ---------------------------------------------------------------------------
// MDLSTM wavefront, TWO CUs per batch (64 blocks):
//   even block (A): rows 0..15;  odd block (B): rows 16..31.
// Dependency is one-directional: B needs A's row-15 h,c of diag d-1 (via a
// 32-slot ring of device-scope atomics + flagA); A only throttles on a ring
// credit (flagB) that B always eventually grants -> NO deadlock possible.
// feat accumulation = fire-and-forget atomicAdd (device-coherent across XCDs).
// Each block runs 271 diagonals (A: 0..270, B: 16..286).
__global__ __launch_bounds__(512)
void mdlstm_kernel(const float* __restrict__ X, const short* __restrict__ wsW,
                   const float* __restrict__ Wx, const float* __restrict__ bias,
                   float* __restrict__ feat, float* __restrict__ bH0,
                   float* __restrict__ bC0, int* __restrict__ flagA,
                   int* __restrict__ flagB) {
  __shared__ __align__(16) short h_buf[2][17][136];   // 9.2 KB (B uses 17 rows)
  __shared__ __align__(16) short wlds[128 * 512];     // 128 KB: gates 3,4
  __shared__ __align__(16) short wlds2[16 * 512];     // 16 KB: gate 2, kk=0,1

  const int blk  = blockIdx.x;
  const int bat  = blk >> 1;
  const bool isB = blk & 1;
  const int tid  = threadIdx.x;
  const int lane = tid & 63;
  const int g    = tid >> 6;
  const int col  = lane & 15;
  const int quad = lane >> 4;
  const int jj   = g * 16 + col;

  for (int i = tid; i < 2 * 17 * 136 / 2; i += 512) ((int*)h_buf)[i] = 0;
  {
    const uint4* src = (const uint4*)(wsW + 192 * 512);  // frags 192.. (q=3,4)
    uint4* dst = (uint4*)wlds;
    for (int i = tid; i < 8192; i += 512) dst[i] = src[i];
    const uint4* s4 = (const uint4*)wsW;                 // gate2 kk=0,1 frags
    uint4* d2 = (uint4*)wlds2;
    for (int i = tid; i < 1024; i += 512) {
      int f = i >> 6, off = i & 63;                      // f = g2*2 + kk
      int srcf = 128 + 8 * (f >> 1) + (f & 1);
      d2[i] = s4[srcf * 64 + off];
    }
  }

  float wx[5], bg[5];
#pragma unroll
  for (int q = 0; q < 5; ++q) {
    wx[q] = Wx[q * 128 + jj];
    bg[q] = bias[q * 128 + jj];
  }
  float cp[4] = {0.f, 0.f, 0.f, 0.f};   // c-state: rows mbase..mbase+3
  float c15 = 0.0f;                      // B only, valid on quad0 lanes

  const float* Xg = X + bat * 8192;
  float* fb = feat + bat * 32768;
  float* bH = bH0 + bat * 32 * 128;
  float* bC = bC0 + bat * 32 * 128;
  int* fA = flagA + bat;
  int* fB = flagB + bat;
  const short8* W8 = (const short8*)wsW;
  const short8* pW0 = W8 + ((0 * 8 + g) * 8) * 64 + lane;
  const short8* pW1 = W8 + ((1 * 8 + g) * 8) * 64 + lane;
  const short8* pW2 = W8 + ((2 * 8 + g) * 8) * 64 + lane;
  const short8* pL3 = (const short8*)&wlds[((0 * 8 + g) * 8) * 512 + lane * 8];
  const short8* pL4 = (const short8*)&wlds[((1 * 8 + g) * 8) * 512 + lane * 8];
  const short8* pL2 = (const short8*)&wlds2[(g * 2) * 512 + lane * 8];
  const int mbase = (isB ? 16 : 0) + quad * 4;           // global row of r=0
  const int widx0 = (isB ? 1 : 0) + quad * 4;            // LDS row of r=0
  const float* pX = Xg - 31 * mbase;                     // + d*32 per diag
  float* pF = fb + jj - 128 * mbase;                     // + d*128 per diag
  __syncthreads();

  auto step = [&](int d, auto isb_, auto allv_) {
    constexpr bool IsB = decltype(isb_)::value;
    constexpr bool ALLV = decltype(allv_)::value;
    const int rbuf = (d + 1) & 1, wbuf = d & 1;
    float4v acc[5];
#pragma unroll
    for (int q = 0; q < 5; ++q) acc[q] = (float4v){bg[q], bg[q], bg[q], bg[q]};
    const short8 z8 = (short8){0, 0, 0, 0, 0, 0, 0, 0};
#pragma unroll
    for (int kk = 0; kk < 8; ++kk) {
      const int up = (kk >= 4) ? 1 : 0;                  // kk<4: h_left; else h_up
      const int cc = (kk & 3) * 32 + quad * 8;
      int row = col + (IsB ? 1 : 0) - up;
      short8 a0 = (IsB || row >= 0) ? *(const short8*)&h_buf[rbuf][row][cc] : z8;
      short8 b3 = pL3[kk * 64];
      acc[3] = __builtin_amdgcn_mfma_f32_16x16x32_bf16(a0, b3, acc[3], 0, 0, 0);
      short8 b4 = pL4[kk * 64];
      acc[4] = __builtin_amdgcn_mfma_f32_16x16x32_bf16(a0, b4, acc[4], 0, 0, 0);
      short8 b2 = (kk < 2) ? pL2[kk * 64] : pW2[kk * 64];
      acc[2] = __builtin_amdgcn_mfma_f32_16x16x32_bf16(a0, b2, acc[2], 0, 0, 0);
      short8 b0 = pW0[kk * 64];
      acc[0] = __builtin_amdgcn_mfma_f32_16x16x32_bf16(a0, b0, acc[0], 0, 0, 0);
      short8 b1 = pW1[kk * 64];
      acc[1] = __builtin_amdgcn_mfma_f32_16x16x32_bf16(a0, b1, acc[1], 0, 0, 0);
    }

    float t0 = __shfl_up(cp[3], 16);
    float cu[4];
    cu[0] = quad ? t0 : (IsB ? c15 : 0.0f);
    cu[1] = cp[0]; cu[2] = cp[1]; cu[3] = cp[2];
    const float* pXd = pX + d * 32;
    float* pFd = pF + d * 128;
    float xm[4];
#pragma unroll
    for (int r = 0; r < 4; ++r) {
      int w = d - (mbase + r);
      if (ALLV || (w >= 0 && w < 256)) xm[r] = pXd[-31 * r];
    }
#pragma unroll
    for (int r = 0; r < 4; ++r) {
      const int w = d - (mbase + r);
      if (ALLV || (w >= 0 && w < 256)) {
        float c_up = cu[r];
        float c_l  = cp[r];
        float x    = xm[r];
        float zi = clamp15(fmaf(x, wx[0], acc[0][r]));
        float zg = clamp15(fmaf(x, wx[1], acc[1][r]));
        float z1 = clamp15(fmaf(x, wx[2], acc[2][r]));
        float z2 = clamp15(fmaf(x, wx[3], acc[3][r]));
        float zo = clamp15(fmaf(x, wx[4], acc[4][r]));
        float e1 = __expf(z1), e2 = __expf(z2), ei = __expf(zi), eg = __expf(2.0f * zg);
        float A1 = 1.0f + e1, A2 = 1.0f + e2, Ai = 1.0f + ei, G = 1.0f + eg;
        float P = Ai * G, Q = A1 * A2;
        float rD = fastrcp(P * Q);
        float c = (e1 * c_l * (A2 * P) + e2 * c_up * (A1 * P) + ei * (eg - 1.0f) * Q) * rD;
        float eo = __expf(-zo);
        float ec = __expf(2.0f * clamp15(c));
        float h = (ec - 1.0f) * fastrcp((1.0f + eo) * (ec + 1.0f));
        cp[r] = c;
        h_buf[wbuf][widx0 + r][jj] = f2bf(h);
        atomicAdd(&pFd[-128 * r], h);                    // device-coherent accumulate
        if (!IsB && r == 3 && quad == 3 && d >= 15) {    // publish row-15 boundary
          const int slot = (d & 31) * 128 + jj;
          atomicExch(&bH[slot], h);
          atomicExch(&bC[slot], c);
        }
      }
    }
  };

  // B: pull boundary bnd[e-1] (A's diag e-1) for use at diag e.
  auto receive = [&](int e) {
    if (e <= 271) {
      if (lane == 0) { while (atomicAdd(fA, 0) < e) {} }  // wave-wide gate
      const int slot = ((e - 1) & 31) * 128 + jj;
      if (quad == 1) {
        float hv = atomicAdd(&bH[slot], 0.0f);
        h_buf[(e + 1) & 1][0][jj] = f2bf(hv);
      } else if (quad == 0) {
        c15 = atomicAdd(&bC[slot], 0.0f);
      }
    } else {                                             // h15/c15 out of range -> 0
      if (quad == 1) h_buf[(e + 1) & 1][0][jj] = 0;
      else if (quad == 0) c15 = 0.0f;
    }
  };

  BC<true> T; BC<false> F;
  if (!isB) {
    for (int d = 0; d < 15; ++d)   { step(d, F, F); __syncthreads(); }
    for (int d = 15; d < 256; ++d) {
      if (d >= 47 && lane == 0) { while (atomicAdd(fB, 0) < d - 32) {} }  // ring credit
      step(d, F, T); __syncthreads();
      if (tid == 0) atomicExch(fA, d + 1);               // bnd[d] visible (post-barrier)
    }
    for (int d = 256; d < 271; ++d) {
      if (lane == 0) { while (atomicAdd(fB, 0) < d - 32) {} }
      step(d, F, F); __syncthreads();
      if (tid == 0) atomicExch(fA, d + 1);
    }
  } else {
    receive(16);
    for (int d = 16; d < 31; ++d)  { __syncthreads(); step(d, T, F); receive(d + 1); if (tid == 0) atomicExch(fB, d); }
    for (int d = 31; d < 272; ++d) { __syncthreads(); step(d, T, T); receive(d + 1); if (tid == 0) atomicExch(fB, d); }
    for (int d = 272; d < 287; ++d){ __syncthreads(); step(d, T, F); if (d < 286) receive(d + 1); if (tid == 0) atomicExch(fB, d); }
  }
}

// ---------------------------------------------------------------------------
// logits = feat @ W_fc + b_fc, then log_softmax -> logp [32][256][101]
__global__ __launch_bounds__(256)
void logits_kernel(const float* __restrict__ feat, const float* __restrict__ Wfc,
                   const float* __restrict__ bfc, float* __restrict__ logp) {
  __shared__ float sW[128 * 101];
  __shared__ float sF[8][128];
  __shared__ float sL[8][104];
  __shared__ float sLse[8];
  const int tid = threadIdx.x;
  const int b  = blockIdx.x >> 5;
  const int t0 = (blockIdx.x & 31) * 8;

  for (int i = tid; i < 128 * 101; i += 256) sW[i] = Wfc[i];
  for (int i = tid; i < 8 * 128; i += 256)
    sF[i >> 7][i & 127] = feat[(b * 256 + t0 + (i >> 7)) * 128 + (i & 127)];
  __syncthreads();
  for (int idx = tid; idx < 8 * 101; idx += 256) {
    int tr = idx / 101, v = idx - tr * 101;
    float s = bfc[v];
#pragma unroll 4
    for (int k = 0; k < 128; ++k) s += sF[tr][k] * sW[k * 101 + v];
    sL[tr][v] = s;
  }
  __syncthreads();
  if (tid < 8) {
    float m = NEGF;
    for (int v = 0; v < 101; ++v) m = fmaxf(m, sL[tid][v]);
    float su = 0.0f;
    for (int v = 0; v < 101; ++v) su += __expf(sL[tid][v] - m);
    sLse[tid] = m + __logf(su);
  }
  __syncthreads();
  for (int idx = tid; idx < 8 * 101; idx += 256) {
    int tr = idx / 101, v = idx - tr * 101;
    logp[(b * 256 + t0 + tr) * 101 + v] = sL[tr][v] - sLse[tr];
  }
}

// ---------------------------------------------------------------------------
// CTC forward: one wave per batch. Lane l holds alpha[s=l]; lane 63 also s=64.
__global__ __launch_bounds__(64)
void ctc_kernel(const float* __restrict__ logp, const int* __restrict__ y,
                float* __restrict__ out) {
  const int b = blockIdx.x;
  const int l = threadIdx.x;
  const float* lpb = logp + b * 256 * 101;
  const int* yb = y + b * 32;
  int lab = (l & 1) ? yb[l >> 1] : 100;                 // ext[s]: odd->label, even->blank
  bool skip = (l & 1) && (l >= 3) && (yb[l >> 1] != yb[(l >> 1) - 1]);

  float a   = (l == 0) ? lpb[100] : ((l == 1) ? lpb[lab] : NEGF);
  float a64 = NEGF;                                      // alpha[64] (valid on lane 63)
  float pl[4], pb[4];
#pragma unroll
  for (int tt = 0; tt < 4; ++tt) {
    pl[tt] = lpb[(1 + tt) * 101 + lab];
    pb[tt] = lpb[(1 + tt) * 101 + 100];
  }
#pragma unroll 4
  for (int t = 1; t < 256; ++t) {
    const int s = (t - 1) & 3;
    float lpl = pl[s], lpbk = pb[s];
    if (t + 4 < 256) {                                   // refill slot with t+4
      pl[s] = lpb[(t + 4) * 101 + lab];
      pb[s] = lpb[(t + 4) * 101 + 100];
    }
    float am1 = __shfl_up(a, 1); if (l == 0) am1 = NEGF;
    float am2 = __shfl_up(a, 2); if (l < 2 || !skip) am2 = NEGF;
    float m3 = fmaxf(a, fmaxf(am1, am2));
    float na = m3 + __logf(__expf(a - m3) + __expf(am1 - m3) + __expf(am2 - m3)) + lpl;
    float m2 = fmaxf(a64, a);                            // s=64: lse(alpha64, alpha63)
    float na64 = m2 + __logf(__expf(a64 - m2) + __expf(a - m2)) + lpbk;
    a = na;
    a64 = na64;
  }
  float A63 = __shfl(a, 63);
  float A64 = __shfl(a64, 63);
  if (l == 0) {
    float m = fmaxf(A63, A64);
    out[b] = -(m + __logf(__expf(A63 - m) + __expf(A64 - m)));
  }
}

// ---------------------------------------------------------------------------
extern "C" void kernel_launch(void* const* d_in, const int* in_sizes, int n_in,
                              void* d_out, int out_size, void* d_ws, size_t ws_size,
                              hipStream_t stream) {
  const float* X   = (const float*)d_in[0];
  const int*   y   = (const int*)d_in[1];
  const float* Wx  = (const float*)d_in[2];
  const float* Wh1 = (const float*)d_in[3];
  const float* Wh2 = (const float*)d_in[4];
  const float* bi  = (const float*)d_in[5];
  const float* Wfc = (const float*)d_in[6];
  const float* bfc = (const float*)d_in[7];
  float* out = (float*)d_out;

  char* ws = (char*)d_ws;
  // Layout (max 0x778000 = 7.83 MB, under the proven R11 footprint):
  //   wsW   0x000000 - 0x050000  (bf16 weight frags)
  //   bndH  0x050000 - 0x0D0000  (32 batches x 32-slot ring x 128 f32)   } dead after
  //   bndC  0x0D0000 - 0x150000                                          } mdlstm ->
  //   flags 0x150000 - 0x151000                                          } overlaid
  //   logp  0x050000 - 0x378000  (written by logits, after mdlstm)       } by logp
  //   feat  0x378000 - 0x778000  (4 MB, atomically accumulated)
  short* wsW  = (short*)(ws);
  float* bndH = (float*)(ws + 0x50000);
  float* bndC = (float*)(ws + 0xD0000);
  int*   flgA = (int*)(ws + 0x150000);
  int*   flgB = (int*)(ws + 0x150800);
  float* logp = (float*)(ws + 0x50000);
  float* feat = (float*)(ws + 0x378000);

  hipMemsetAsync(feat, 0, 32 * 256 * 128 * sizeof(float), stream);  // atomics accumulate onto 0
  prep_w_kernel<<<80, 256, 0, stream>>>(Wh1, Wh2, wsW);
  mdlstm_kernel<<<64, 512, 0, stream>>>(X, wsW, Wx, bi, feat, bndH, bndC, flgA, flgB);
  logits_kernel<<<1024, 256, 0, stream>>>(feat, Wfc, bfc, logp);
  ctc_kernel<<<32, 64, 0, stream>>>(logp, y, out);
}